// Round 3
// baseline (2408.808 us; speedup 1.0000x reference)
//
#include <hip/hip_runtime.h>
#include <hip/hip_bf16.h>
#include <math.h>

typedef __hip_bfloat16 bf16;

#define BN_SCALE 0.9999950000374997f
#define NPTS 1024
#define NB 4

__device__ __forceinline__ float b2f(bf16 v) { return __bfloat162float(v); }
// dtype-flag-aware load: isf=1 -> fp32 data, isf=0 -> bf16 data
__device__ __forceinline__ float ldw(const void* p, size_t i, int isf) {
    return isf ? ((const float*)p)[i] : b2f(((const bf16*)p)[i]);
}

// ---------------- dtype probe: detect fp32 (1) vs bf16 (0) ----------------
__global__ void k_probe(const void* xraw, int* flag) {
    __shared__ int cnt[256];
    const unsigned short* u = (const unsigned short*)xraw;
    int t = threadIdx.x, c = 0;
    for (int i = t; i < 8192; i += 256) {
        unsigned short v = u[i];
        int e = (v >> 7) & 0xFF;
        int m = v & 0x7F;
        // implausible as bf16 drawn from N(0,1): inf/nan, |v|>=2^14, denormal
        if (e == 0xFF || e >= 141 || (e == 0 && m != 0)) c++;
    }
    cnt[t] = c; __syncthreads();
    for (int off = 128; off > 0; off >>= 1) {
        if (t < off) cnt[t] += cnt[t + off];
        __syncthreads();
    }
    if (t == 0) *flag = (cnt[0] > 200) ? 1 : 0;
}

// ---------------- convert x -> fp32 ----------------
__global__ void k_cvt(const void* src, float* dst, int n, const int* flag) {
    int i = blockIdx.x * 256 + threadIdx.x;
    int isf = *flag;
    if (i < n) dst[i] = ldw(src, i, isf);
}

// ---------------- per-batch squared norms ----------------
__global__ void k_sq(const float* __restrict__ X, int ld, int C, float* __restrict__ sq) {
    int i = blockIdx.x * 256 + threadIdx.x;  // i < 1024
    if (i < NPTS) {
        const float* row = X + (size_t)i * ld;
        float a = 0.f;
        for (int c = 0; c < C; c++) { float v = row[c]; a += v * v; }
        sq[i] = a;
    }
}

// ---------------- per-batch pairwise d = 2*dot - sq_n - sq_m ----------------
__global__ void k_dist(const float* __restrict__ Xb, int ld, int C,
                       const float* __restrict__ sqb, float* __restrict__ D) {
    __shared__ float Xn[16][17], Xm[16][17];
    int n0 = blockIdx.y * 16, m0 = blockIdx.x * 16;
    int ty = threadIdx.y, tx = threadIdx.x;
    float acc = 0.f;
    for (int c0 = 0; c0 < C; c0 += 16) {
        int c = c0 + tx;
        Xn[ty][tx] = (c < C) ? Xb[(size_t)(n0 + ty) * ld + c] : 0.f;
        Xm[ty][tx] = (c < C) ? Xb[(size_t)(m0 + ty) * ld + c] : 0.f;
        __syncthreads();
#pragma unroll
        for (int kk = 0; kk < 16; kk++) acc += Xn[ty][kk] * Xm[tx][kk];
        __syncthreads();
    }
    int n = n0 + ty, m = m0 + tx;
    D[(size_t)n * NPTS + m] = 2.f * acc - sqb[n] - sqb[m];
}

// ---------------- per-batch top-k (k=20), jax tie-break ----------------
__global__ void k_topk(const float* __restrict__ D, int* __restrict__ idx) {
    __shared__ float vals[NPTS];
    __shared__ float rv[256];
    __shared__ int ri[256];
    int row = blockIdx.x;
    int t = threadIdx.x;
    const float* Drow = D + (size_t)row * NPTS;
    for (int i = t; i < NPTS; i += 256) vals[i] = Drow[i];
    __syncthreads();
    for (int s = 0; s < 20; s++) {
        float bv = -__builtin_inff(); int bi = 0;
        for (int i = t; i < NPTS; i += 256) {
            float v = vals[i];
            if (v > bv) { bv = v; bi = i; }   // ascending scan keeps min index on tie
        }
        rv[t] = bv; ri[t] = bi;
        __syncthreads();
        for (int off = 128; off > 0; off >>= 1) {
            if (t < off) {
                float ov = rv[t + off]; int oi = ri[t + off];
                if (ov > rv[t] || (ov == rv[t] && oi < ri[t])) { rv[t] = ov; ri[t] = oi; }
            }
            __syncthreads();
        }
        if (t == 0) { idx[row * 20 + s] = ri[0]; vals[ri[0]] = -__builtin_inff(); }
        __syncthreads();
    }
}

// ---------------- per-batch s/t GEMM: s[m,o]=Wa.x[m], t[m,o]=(Wb-Wa).x[m] ----------------
// W is (O, 2C) row-major, dtype per flag.
__global__ void k_st(const float* __restrict__ Xb, int ldx, const void* __restrict__ W,
                     int C, int O, float* __restrict__ Sout, float* __restrict__ Tout,
                     const int* __restrict__ flag) {
    __shared__ float Xs[16][17], Vs[16][17];
    int isf = *flag;
    int m0 = blockIdx.y * 16, o20 = blockIdx.x * 16;
    int ty = threadIdx.y, tx = threadIdx.x;
    float acc = 0.f;
    for (int c0 = 0; c0 < C; c0 += 16) {
        int c = c0 + tx;
        Xs[ty][tx] = (c < C) ? Xb[(size_t)(m0 + ty) * ldx + c] : 0.f;
        int o2 = o20 + ty;
        float w = 0.f;
        if (c < C) {
            if (o2 < O) w = ldw(W, (size_t)o2 * 2 * C + c, isf);
            else {
                size_t base = (size_t)(o2 - O) * 2 * C;
                w = ldw(W, base + C + c, isf) - ldw(W, base + c, isf);
            }
        }
        Vs[ty][tx] = w;
        __syncthreads();
#pragma unroll
        for (int kk = 0; kk < 16; kk++) acc += Xs[ty][kk] * Vs[tx][kk];
        __syncthreads();
    }
    int m = m0 + ty, o2 = o20 + tx;
    if (o2 < O) Sout[(size_t)m * O + o2] = acc;
    else        Tout[(size_t)m * O + (o2 - O)] = acc;
}

// ---------------- per-batch gather + affine + lrelu + max over k -> xc slice (fp32) ----------------
__global__ void k_gmax(const float* __restrict__ S, const float* __restrict__ Tm,
                       const int* __restrict__ idx, const void* __restrict__ g,
                       const void* __restrict__ bias, int O,
                       float* __restrict__ xcOut, const int* __restrict__ flag) {
    __shared__ int id[20];
    int isf = *flag;
    int n = blockIdx.x;
    int o = threadIdx.x;  // blockDim.x == O
    if (o < 20) id[o] = idx[n * 20 + o];
    __syncthreads();
    float tv = Tm[(size_t)n * O + o];
    float scl = ldw(g, o, isf) * BN_SCALE;
    float bi = ldw(bias, o, isf);
    float acc = -__builtin_inff();
    for (int j = 0; j < 20; j++) {
        int m = id[j];
        float v = S[(size_t)m * O + o] + tv;
        float z = v * scl + bi;
        z = z > 0.f ? z : 0.2f * z;
        acc = fmaxf(acc, z);
    }
    xcOut[(size_t)n * 960 + o] = acc;
}

// ---------------- per-batch conv5 GEMM: Y[m,o] = sum_c xc[m,c]*W5[o,c] ----------------
__global__ void k_gemm5(const float* __restrict__ Xb, const void* __restrict__ W,
                        float* __restrict__ Y, const int* __restrict__ flag) {
    __shared__ float Xs[16][17], Ws[16][17];
    int isf = *flag;
    int m0 = blockIdx.y * 16, o0 = blockIdx.x * 16;
    int ty = threadIdx.y, tx = threadIdx.x;
    float acc = 0.f;
    for (int c0 = 0; c0 < 960; c0 += 16) {
        int c = c0 + tx;
        Xs[ty][tx] = Xb[(size_t)(m0 + ty) * 960 + c];
        Ws[ty][tx] = ldw(W, (size_t)(o0 + ty) * 960 + c, isf);
        __syncthreads();
#pragma unroll
        for (int kk = 0; kk < 16; kk++) acc += Xs[ty][kk] * Ws[tx][kk];
        __syncthreads();
    }
    Y[(size_t)(m0 + ty) * 512 + (o0 + tx)] = acc;
}

// ---------------- per-batch conv5 epilogue: affine + lrelu + max over n ----------------
__global__ void k_pool(const float* __restrict__ Yb, const void* __restrict__ g,
                       const void* __restrict__ bias, float* __restrict__ pooledb,
                       const int* __restrict__ flag) {
    int isf = *flag;
    int o = blockIdx.x * 256 + threadIdx.x;  // < 512
    float scl = ldw(g, o, isf) * BN_SCALE, bi = ldw(bias, o, isf);
    float acc = -__builtin_inff();
    for (int n = 0; n < NPTS; n++) {
        float v = Yb[(size_t)n * 512 + o] * scl + bi;
        v = v > 0.f ? v : 0.2f * v;
        acc = fmaxf(acc, v);
    }
    pooledb[o] = acc;
}

// ---------------- final linear: out[b,f] = sum_o pooled[b,o] * We[f,o] ----------------
__global__ void k_final(const float* __restrict__ pooled, const void* __restrict__ We,
                        void* __restrict__ out, const int* __restrict__ flag) {
    __shared__ float p[512];
    int isf = *flag;
    int b = blockIdx.x;
    int f = threadIdx.x;  // 256
    for (int i = threadIdx.x; i < 512; i += 256) p[i] = pooled[b * 512 + i];
    __syncthreads();
    float acc = 0.f;
    for (int o = 0; o < 512; o++) acc += p[o] * ldw(We, (size_t)f * 512 + o, isf);
    if (isf) ((float*)out)[b * 256 + f] = acc;
    else     ((bf16*)out)[b * 256 + f] = __float2bfloat16(acc);
}

extern "C" void kernel_launch(void* const* d_in, const int* in_sizes, int n_in,
                              void* d_out, int out_size, void* d_ws, size_t ws_size,
                              hipStream_t stream) {
    const void* x  = d_in[0];
    const void* Wl[4] = { d_in[1], d_in[4], d_in[7], d_in[10] };
    const void* gl[4] = { d_in[2], d_in[5], d_in[8], d_in[11] };
    const void* bl[4] = { d_in[3], d_in[6], d_in[9], d_in[12] };
    const void* W5 = d_in[13];
    const void* g5 = d_in[14];
    const void* b5 = d_in[15];
    const void* We = d_in[16];

    // workspace layout (float-slot offsets), total ~2,067,472 floats = 8.27 MB
    float* ws     = (float*)d_ws;
    float* xF     = ws;                    // 12,288
    float* xcb    = ws + 12288;            // 1024*960 = 983,040 (per-batch concat feat)
    float* DST    = ws + 995328;           // 1,048,576 (D | s+t | Yb)
    int*   idxb   = (int*)(ws + 2043904);  // 1024*20
    float* pooled = ws + 2064384;          // 2048
    float* sq     = ws + 2066432;          // 1024
    int*   flag   = (int*)(ws + 2067456);

    k_probe<<<1, 256, 0, stream>>>(x, flag);
    k_cvt<<<48, 256, 0, stream>>>(x, xF, NB * NPTS * 3, flag);

    const int Cs[4]     = { 3, 64, 128, 256 };
    const int Os[4]     = { 64, 128, 256, 512 };
    const int colIn[4]  = { 0, 0, 64, 192 };
    const int colOut[4] = { 0, 64, 192, 448 };

    for (int b = 0; b < NB; b++) {
        for (int l = 0; l < 4; l++) {
            int C = Cs[l], O = Os[l];
            const float* Xb = (l == 0) ? (xF + (size_t)b * NPTS * 3) : (xcb + colIn[l]);
            int ld = (l == 0) ? 3 : 960;
            float* sbuf = DST;
            float* tbuf = DST + (size_t)NPTS * O;
            k_sq<<<4, 256, 0, stream>>>(Xb, ld, C, sq);
            k_dist<<<dim3(64, 64), dim3(16, 16), 0, stream>>>(Xb, ld, C, sq, DST);
            k_topk<<<NPTS, 256, 0, stream>>>(DST, idxb);
            k_st<<<dim3(2 * O / 16, NPTS / 16), dim3(16, 16), 0, stream>>>(
                Xb, ld, Wl[l], C, O, sbuf, tbuf, flag);
            k_gmax<<<NPTS, O, 0, stream>>>(sbuf, tbuf, idxb, gl[l], bl[l], O,
                                           xcb + colOut[l], flag);
        }
        k_gemm5<<<dim3(32, 64), dim3(16, 16), 0, stream>>>(xcb, W5, DST, flag);
        k_pool<<<2, 256, 0, stream>>>(DST, g5, b5, pooled + b * 512, flag);
    }
    k_final<<<NB, 256, 0, stream>>>(pooled, We, d_out, flag);
}

// Round 4
// 1909.588 us; speedup vs baseline: 1.2614x; 1.2614x over previous
//
#include <hip/hip_runtime.h>
#include <hip/hip_bf16.h>
#include <math.h>

typedef __hip_bfloat16 bf16;

#define BN_SCALE 0.9999950000374997f
#define NPTS 1024
#define NB 4

__device__ __forceinline__ float b2f(bf16 v) { return __bfloat162float(v); }
// dtype-flag-aware load: isf=1 -> fp32 data, isf=0 -> bf16 data
__device__ __forceinline__ float ldw(const void* p, size_t i, int isf) {
    return isf ? ((const float*)p)[i] : b2f(((const bf16*)p)[i]);
}

// ---------------- dtype probe: detect fp32 (1) vs bf16 (0) ----------------
__global__ void k_probe(const void* xraw, int* flag) {
    __shared__ int cnt[256];
    const unsigned short* u = (const unsigned short*)xraw;
    int t = threadIdx.x, c = 0;
    for (int i = t; i < 8192; i += 256) {
        unsigned short v = u[i];
        int e = (v >> 7) & 0xFF;
        int m = v & 0x7F;
        if (e == 0xFF || e >= 141 || (e == 0 && m != 0)) c++;
    }
    cnt[t] = c; __syncthreads();
    for (int off = 128; off > 0; off >>= 1) {
        if (t < off) cnt[t] += cnt[t + off];
        __syncthreads();
    }
    if (t == 0) *flag = (cnt[0] > 200) ? 1 : 0;
}

// ---------------- convert x -> fp32 ----------------
__global__ void k_cvt(const void* src, float* dst, int n, const int* flag) {
    int i = blockIdx.x * 256 + threadIdx.x;
    int isf = *flag;
    if (i < n) dst[i] = ldw(src, i, isf);
}

// ---------------- per-batch squared norms ----------------
__global__ void k_sq(const float* __restrict__ X, int ld, int C, float* __restrict__ sq) {
    int i = blockIdx.x * 256 + threadIdx.x;
    if (i < NPTS) {
        const float* row = X + (size_t)i * ld;
        float a = 0.f;
        for (int c = 0; c < C; c++) { float v = row[c]; a += v * v; }
        sq[i] = a;
    }
}

// ============ micro-tiled fp32 GEMM building block: 64x64 tile, 4x4/thread ============
// Block: 256 threads. As/Bs are k-major [16][68] (pad 68 keeps 16B align, spreads banks).

// ---------------- pairwise d = 2*dot - sq_n - sq_m, symmetric (upper tiles only) ----------------
__global__ void k_dist(const float* __restrict__ Xb, int ld, int C,
                       const float* __restrict__ sqb, float* __restrict__ D) {
    int bx = blockIdx.x, by = blockIdx.y;
    if (bx < by) return;  // symmetry: compute m-tile >= n-tile, mirror-store
    __shared__ float As[16][68], Bs[16][68];
    int t = threadIdx.x;
    int r0 = (t >> 4) << 2, c0 = (t & 15) << 2;
    int mld = t & 63, kq = (t >> 6) << 2;
    int n0 = by * 64, m0 = bx * 64;
    float acc[4][4] = {};
    for (int k0 = 0; k0 < C; k0 += 16) {
#pragma unroll
        for (int j = 0; j < 4; j++) {
            int c = k0 + kq + j;
            As[kq + j][mld] = (c < C) ? Xb[(size_t)(n0 + mld) * ld + c] : 0.f;
            Bs[kq + j][mld] = (c < C) ? Xb[(size_t)(m0 + mld) * ld + c] : 0.f;
        }
        __syncthreads();
#pragma unroll
        for (int kk = 0; kk < 16; kk++) {
            float4 a4 = *(const float4*)&As[kk][r0];
            float4 b4 = *(const float4*)&Bs[kk][c0];
            float av[4] = { a4.x, a4.y, a4.z, a4.w };
            float bv[4] = { b4.x, b4.y, b4.z, b4.w };
#pragma unroll
            for (int i = 0; i < 4; i++)
#pragma unroll
                for (int j = 0; j < 4; j++) acc[i][j] += av[i] * bv[j];
        }
        __syncthreads();
    }
    float sn[4], sm[4];
#pragma unroll
    for (int i = 0; i < 4; i++) sn[i] = sqb[n0 + r0 + i];
#pragma unroll
    for (int j = 0; j < 4; j++) sm[j] = sqb[m0 + c0 + j];
    float d[4][4];
#pragma unroll
    for (int i = 0; i < 4; i++)
#pragma unroll
        for (int j = 0; j < 4; j++) d[i][j] = 2.f * acc[i][j] - sn[i] - sm[j];
#pragma unroll
    for (int i = 0; i < 4; i++) {
        float4 v = make_float4(d[i][0], d[i][1], d[i][2], d[i][3]);
        *(float4*)&D[(size_t)(n0 + r0 + i) * NPTS + m0 + c0] = v;
    }
    if (bx != by) {
#pragma unroll
        for (int i = 0; i < 4; i++)
#pragma unroll
            for (int j = 0; j < 4; j++)
                D[(size_t)(m0 + c0 + j) * NPTS + n0 + r0 + i] = d[i][j];
    }
}

// ---------------- top-k (k=20): one wave per row, shuffle reduction ----------------
__global__ void k_topk(const float* __restrict__ D, int* __restrict__ idx) {
    __shared__ float vals[4][NPTS];
    int w = threadIdx.x >> 6, l = threadIdx.x & 63;
    int row = blockIdx.x * 4 + w;
    const float* Dr = D + (size_t)row * NPTS;
    for (int j = 0; j < 16; j++) vals[w][j * 64 + l] = Dr[j * 64 + l];
    __syncthreads();
    for (int s = 0; s < 20; s++) {
        float bv = -__builtin_inff(); int bi = 0;
#pragma unroll
        for (int j = 0; j < 16; j++) {
            int i = j * 64 + l;
            float v = vals[w][i];
            if (v > bv) { bv = v; bi = i; }
        }
#pragma unroll
        for (int off = 32; off > 0; off >>= 1) {
            float ov = __shfl_down(bv, off);
            int   oi = __shfl_down(bi, off);
            if (ov > bv || (ov == bv && oi < bi)) { bv = ov; bi = oi; }
        }
        if (l == 0) { idx[row * 20 + s] = bi; vals[w][bi] = -__builtin_inff(); }
        __syncthreads();
    }
}

// ---------------- s/t GEMM into combined ST[m][2O]: cols [0,O)=Wa.x, [O,2O)=(Wb-Wa).x ----------------
__global__ void k_st(const float* __restrict__ Xb, int ld, const void* __restrict__ W,
                     int C, int O, float* __restrict__ ST, const int* __restrict__ flag) {
    __shared__ float As[16][68], Bs[16][68];
    int isf = *flag;
    int t = threadIdx.x;
    int r0 = (t >> 4) << 2, c0 = (t & 15) << 2;
    int mld = t & 63, kq = (t >> 6) << 2;
    int m0 = blockIdx.y * 64, o20 = blockIdx.x * 64;
    int N = 2 * O;
    float acc[4][4] = {};
    for (int k0 = 0; k0 < C; k0 += 16) {
#pragma unroll
        for (int j = 0; j < 4; j++) {
            int c = k0 + kq + j;
            As[kq + j][mld] = (c < C) ? Xb[(size_t)(m0 + mld) * ld + c] : 0.f;
            int o2 = o20 + mld;
            float wv = 0.f;
            if (c < C) {
                if (o2 < O) wv = ldw(W, (size_t)o2 * 2 * C + c, isf);
                else {
                    size_t base = (size_t)(o2 - O) * 2 * C;
                    wv = ldw(W, base + C + c, isf) - ldw(W, base + c, isf);
                }
            }
            Bs[kq + j][mld] = wv;
        }
        __syncthreads();
#pragma unroll
        for (int kk = 0; kk < 16; kk++) {
            float4 a4 = *(const float4*)&As[kk][r0];
            float4 b4 = *(const float4*)&Bs[kk][c0];
            float av[4] = { a4.x, a4.y, a4.z, a4.w };
            float bv[4] = { b4.x, b4.y, b4.z, b4.w };
#pragma unroll
            for (int i = 0; i < 4; i++)
#pragma unroll
                for (int j = 0; j < 4; j++) acc[i][j] += av[i] * bv[j];
        }
        __syncthreads();
    }
#pragma unroll
    for (int i = 0; i < 4; i++) {
        float4 v = make_float4(acc[i][0], acc[i][1], acc[i][2], acc[i][3]);
        *(float4*)&ST[(size_t)(m0 + r0 + i) * N + o20 + c0] = v;
    }
}

// ---------------- gather + affine + lrelu + max over k -> xc slice ----------------
__global__ void k_gmax(const float* __restrict__ ST, const int* __restrict__ idx,
                       const void* __restrict__ g, const void* __restrict__ bias, int O,
                       float* __restrict__ xcOut, const int* __restrict__ flag) {
    __shared__ int id[20];
    int isf = *flag;
    int n = blockIdx.x;
    int o = threadIdx.x;  // blockDim.x == O
    if (o < 20) id[o] = idx[n * 20 + o];
    __syncthreads();
    int N = 2 * O;
    float tv = ST[(size_t)n * N + O + o];
    float scl = ldw(g, o, isf) * BN_SCALE;
    float bi = ldw(bias, o, isf);
    float acc = -__builtin_inff();
    for (int j = 0; j < 20; j++) {
        int m = id[j];
        float v = ST[(size_t)m * N + o] + tv;
        float z = v * scl + bi;
        z = z > 0.f ? z : 0.2f * z;
        acc = fmaxf(acc, z);
    }
    xcOut[(size_t)n * 960 + o] = acc;
}

// ---------------- conv5 GEMM: Y[m][o] = sum_c xc[m][c] * W5[o][c] ----------------
__global__ void k_gemm5(const float* __restrict__ Xb, const void* __restrict__ W,
                        float* __restrict__ Y, const int* __restrict__ flag) {
    __shared__ float As[16][68], Bs[16][68];
    int isf = *flag;
    int t = threadIdx.x;
    int r0 = (t >> 4) << 2, c0 = (t & 15) << 2;
    int mld = t & 63, kq = (t >> 6) << 2;
    int m0 = blockIdx.y * 64, o0 = blockIdx.x * 64;
    float acc[4][4] = {};
    for (int k0 = 0; k0 < 960; k0 += 16) {
#pragma unroll
        for (int j = 0; j < 4; j++) {
            int c = k0 + kq + j;
            As[kq + j][mld] = Xb[(size_t)(m0 + mld) * 960 + c];
            Bs[kq + j][mld] = ldw(W, (size_t)(o0 + mld) * 960 + c, isf);
        }
        __syncthreads();
#pragma unroll
        for (int kk = 0; kk < 16; kk++) {
            float4 a4 = *(const float4*)&As[kk][r0];
            float4 b4 = *(const float4*)&Bs[kk][c0];
            float av[4] = { a4.x, a4.y, a4.z, a4.w };
            float bv[4] = { b4.x, b4.y, b4.z, b4.w };
#pragma unroll
            for (int i = 0; i < 4; i++)
#pragma unroll
                for (int j = 0; j < 4; j++) acc[i][j] += av[i] * bv[j];
        }
        __syncthreads();
    }
#pragma unroll
    for (int i = 0; i < 4; i++) {
        float4 v = make_float4(acc[i][0], acc[i][1], acc[i][2], acc[i][3]);
        *(float4*)&Y[(size_t)(m0 + r0 + i) * 512 + o0 + c0] = v;
    }
}

// ---------------- conv5 epilogue: affine + lrelu + max over n (parallel) ----------------
__global__ void k_pool(const float* __restrict__ Yb, const void* __restrict__ g,
                       const void* __restrict__ bias, float* __restrict__ pooledb,
                       const int* __restrict__ flag) {
    __shared__ float red[4][64];
    int isf = *flag;
    int tx = threadIdx.x & 63, ty = threadIdx.x >> 6;
    int o = blockIdx.x * 64 + tx;
    float scl = ldw(g, o, isf) * BN_SCALE, bi = ldw(bias, o, isf);
    float acc = -__builtin_inff();
    for (int n = ty; n < NPTS; n += 4) {
        float v = Yb[(size_t)n * 512 + o] * scl + bi;
        v = v > 0.f ? v : 0.2f * v;
        acc = fmaxf(acc, v);
    }
    red[ty][tx] = acc;
    __syncthreads();
    if (ty == 0) {
#pragma unroll
        for (int q = 1; q < 4; q++) acc = fmaxf(acc, red[q][tx]);
        pooledb[o] = acc;
    }
}

// ---------------- final linear ----------------
__global__ void k_final(const float* __restrict__ pooled, const void* __restrict__ We,
                        void* __restrict__ out, const int* __restrict__ flag) {
    __shared__ float p[512];
    int isf = *flag;
    int b = blockIdx.x;
    int f = threadIdx.x;
    for (int i = threadIdx.x; i < 512; i += 256) p[i] = pooled[b * 512 + i];
    __syncthreads();
    float acc = 0.f;
    for (int o = 0; o < 512; o++) acc += p[o] * ldw(We, (size_t)f * 512 + o, isf);
    if (isf) ((float*)out)[b * 256 + f] = acc;
    else     ((bf16*)out)[b * 256 + f] = __float2bfloat16(acc);
}

extern "C" void kernel_launch(void* const* d_in, const int* in_sizes, int n_in,
                              void* d_out, int out_size, void* d_ws, size_t ws_size,
                              hipStream_t stream) {
    const void* x  = d_in[0];
    const void* Wl[4] = { d_in[1], d_in[4], d_in[7], d_in[10] };
    const void* gl[4] = { d_in[2], d_in[5], d_in[8], d_in[11] };
    const void* bl[4] = { d_in[3], d_in[6], d_in[9], d_in[12] };
    const void* W5 = d_in[13];
    const void* g5 = d_in[14];
    const void* b5 = d_in[15];
    const void* We = d_in[16];

    // workspace layout (float-slot offsets), total 2,067,457 floats = 8.27 MB (ws is ~8 MiB)
    float* ws     = (float*)d_ws;
    float* xF     = ws;                    // 12,288
    float* xcb    = ws + 12288;            // 1024*960 = 983,040 (per-batch concat feat)
    float* DST    = ws + 995328;           // 1,048,576 (D | ST | Y)
    int*   idxb   = (int*)(ws + 2043904);  // 1024*20
    float* pooled = ws + 2064384;          // 2048
    float* sq     = ws + 2066432;          // 1024
    int*   flag   = (int*)(ws + 2067456);

    k_probe<<<1, 256, 0, stream>>>(x, flag);
    k_cvt<<<48, 256, 0, stream>>>(x, xF, NB * NPTS * 3, flag);

    const int Cs[4]     = { 3, 64, 128, 256 };
    const int Os[4]     = { 64, 128, 256, 512 };
    const int colIn[4]  = { 0, 0, 64, 192 };
    const int colOut[4] = { 0, 64, 192, 448 };

    for (int b = 0; b < NB; b++) {
        for (int l = 0; l < 4; l++) {
            int C = Cs[l], O = Os[l];
            const float* Xb = (l == 0) ? (xF + (size_t)b * NPTS * 3) : (xcb + colIn[l]);
            int ld = (l == 0) ? 3 : 960;
            k_sq<<<4, 256, 0, stream>>>(Xb, ld, C, sq);
            k_dist<<<dim3(16, 16), 256, 0, stream>>>(Xb, ld, C, sq, DST);
            k_topk<<<NPTS / 4, 256, 0, stream>>>(DST, idxb);
            k_st<<<dim3(2 * O / 64, 16), 256, 0, stream>>>(Xb, ld, Wl[l], C, O, DST, flag);
            k_gmax<<<NPTS, O, 0, stream>>>(DST, idxb, gl[l], bl[l], O, xcb + colOut[l], flag);
        }
        k_gemm5<<<dim3(8, 16), 256, 0, stream>>>(xcb, W5, DST, flag);
        k_pool<<<8, 256, 0, stream>>>(DST, g5, b5, pooled + b * 512, flag);
    }
    k_final<<<NB, 256, 0, stream>>>(pooled, We, d_out, flag);
}

// Round 6
// 1197.806 us; speedup vs baseline: 2.0110x; 1.5942x over previous
//
#include <hip/hip_runtime.h>
#include <hip/hip_bf16.h>
#include <math.h>

typedef __hip_bfloat16 bf16;
typedef __bf16 v8bf __attribute__((ext_vector_type(8)));
typedef float v4f __attribute__((ext_vector_type(4)));

#define BN_SCALE 0.9999950000374997f
#define NPTS 1024
#define NB 4
#define TW 40  // LDS tile row stride in bf16 (80B: 2-way bank alias only = free)

__device__ __forceinline__ float b2f(bf16 v) { return __bfloat162float(v); }
__device__ __forceinline__ bf16 f2b(float v) { return __float2bfloat16(v); }
// dtype-flag-aware load: isf=1 -> fp32 data, isf=0 -> bf16 data
__device__ __forceinline__ float ldw(const void* p, size_t i, int isf) {
    return isf ? ((const float*)p)[i] : b2f(((const bf16*)p)[i]);
}

// ---------------- dtype probe: detect fp32 (1) vs bf16 (0) ----------------
__global__ void k_probe(const void* xraw, int* flag) {
    __shared__ int cnt[256];
    const unsigned short* u = (const unsigned short*)xraw;
    int t = threadIdx.x, c = 0;
    for (int i = t; i < 8192; i += 256) {
        unsigned short v = u[i];
        int e = (v >> 7) & 0xFF;
        int m = v & 0x7F;
        if (e == 0xFF || e >= 141 || (e == 0 && m != 0)) c++;
    }
    cnt[t] = c; __syncthreads();
    for (int off = 128; off > 0; off >>= 1) {
        if (t < off) cnt[t] += cnt[t + off];
        __syncthreads();
    }
    if (t == 0) *flag = (cnt[0] > 200) ? 1 : 0;
}

// fill a 64x32 bf16 tile (rows stride ld in global) into LDS [64][TW]; 256 threads, 16B each
__device__ __forceinline__ void fillA(bf16* dst, const bf16* srcRowBase, int ld) {
    int t = threadIdx.x; int r = t >> 2; int kq = (t & 3) << 3;
    *(float4*)(dst + r * TW + kq) = *(const float4*)(srcRowBase + (size_t)r * ld + kq);
}

// load MFMA fragment: sub-tile 'sub' (16 rows), lane l: row=sub*16+(l&15), k=(l>>4)*8
__device__ __forceinline__ v8bf ldfrag(const bf16* tile, int sub, int l) {
    return *(const v8bf*)(tile + (size_t)(sub * 16 + (l & 15)) * TW + ((l >> 4) << 3));
}

// ---------------- layer-1 prep: pad x to 32 cols as hi/lo bf16 split, compute sq ----------------
__global__ void k_xpad(const void* __restrict__ x, int base, const int* __restrict__ flag,
                       bf16* __restrict__ xph, bf16* __restrict__ xpl, float* __restrict__ sq) {
    int isf = *flag;
    int n = blockIdx.x * 256 + threadIdx.x;
    if (n >= NPTS) return;
    float s = 0.f;
    for (int c = 0; c < 32; c++) {
        float v = (c < 3) ? ldw(x, (size_t)base + n * 3 + c, isf) : 0.f;
        bf16 h = f2b(v);
        xph[n * 32 + c] = h;
        xpl[n * 32 + c] = f2b(v - b2f(h));
        s += v * v;
    }
    sq[n] = s;
}

// ---------------- pairwise d = 2*dot - sq_n - sq_m via MFMA (hi/lo split), symmetric ----------------
__global__ __launch_bounds__(256) void k_dist(const bf16* __restrict__ Xhi, const bf16* __restrict__ Xlo,
                                              int ld, int K,
                                              const float* __restrict__ sq, float* __restrict__ D) {
    int bx = blockIdx.x, by = blockIdx.y;
    if (bx < by) return;
    __shared__ alignas(16) bf16 Ah[64 * TW], Al[64 * TW], Bh[64 * TW], Bl[64 * TW];
    int n0 = by * 64, m0 = bx * 64;
    int w = threadIdx.x >> 6, l = threadIdx.x & 63;
    v4f zero = {0.f, 0.f, 0.f, 0.f};
    v4f acc[4] = {zero, zero, zero, zero};
    for (int k0 = 0; k0 < K; k0 += 32) {
        __syncthreads();
        fillA(Ah, Xhi + (size_t)n0 * ld + k0, ld);
        fillA(Bh, Xhi + (size_t)m0 * ld + k0, ld);
        fillA(Al, Xlo + (size_t)n0 * ld + k0, ld);
        fillA(Bl, Xlo + (size_t)m0 * ld + k0, ld);
        __syncthreads();
        v8bf ah = ldfrag(Ah, w, l);
        v8bf al = ldfrag(Al, w, l);
#pragma unroll
        for (int nt = 0; nt < 4; nt++) {
            v8bf bh = ldfrag(Bh, nt, l);
            v8bf bl = ldfrag(Bl, nt, l);
            acc[nt] = __builtin_amdgcn_mfma_f32_16x16x32_bf16(ah, bh, acc[nt], 0, 0, 0);
            acc[nt] = __builtin_amdgcn_mfma_f32_16x16x32_bf16(ah, bl, acc[nt], 0, 0, 0);
            acc[nt] = __builtin_amdgcn_mfma_f32_16x16x32_bf16(al, bh, acc[nt], 0, 0, 0);
        }
    }
    int quad = l >> 4, col = l & 15;
    int nb = n0 + 16 * w + quad * 4;
    float sm[4];
#pragma unroll
    for (int nt = 0; nt < 4; nt++) sm[nt] = sq[m0 + nt * 16 + col];
#pragma unroll
    for (int r = 0; r < 4; r++) {
        float sn = sq[nb + r];
#pragma unroll
        for (int nt = 0; nt < 4; nt++) {
            float d = 2.f * acc[nt][r] - sn - sm[nt];
            int m = m0 + nt * 16 + col;
            D[(size_t)(nb + r) * NPTS + m] = d;
            if (bx != by) D[(size_t)m * NPTS + nb + r] = d;
        }
    }
}

// ---------------- top-k (k=20): one wave per row, jax tie-break ----------------
__global__ void k_topk(const float* __restrict__ D, int* __restrict__ idx) {
    __shared__ float vals[4][NPTS];
    int w = threadIdx.x >> 6, l = threadIdx.x & 63;
    int row = blockIdx.x * 4 + w;
    const float* Dr = D + (size_t)row * NPTS;
    for (int j = 0; j < 16; j++) vals[w][j * 64 + l] = Dr[j * 64 + l];
    __syncthreads();
    for (int s = 0; s < 20; s++) {
        float bv = -__builtin_inff(); int bi = 0;
#pragma unroll
        for (int j = 0; j < 16; j++) {
            int i = j * 64 + l;
            float v = vals[w][i];
            if (v > bv) { bv = v; bi = i; }
        }
#pragma unroll
        for (int off = 32; off > 0; off >>= 1) {
            float ov = __shfl_down(bv, off);
            int   oi = __shfl_down(bi, off);
            if (ov > bv || (ov == bv && oi < bi)) { bv = ov; bi = oi; }
        }
        if (l == 0) { idx[row * 20 + s] = bi; vals[w][bi] = -__builtin_inff(); }
        __syncthreads();
    }
}

// ---------------- st via MFMA: P[m][0:O)=Wa.x, P[m][O:2O)=Wb.x (W dtype per flag) ----------------
__global__ __launch_bounds__(256) void k_st(const bf16* __restrict__ Xhi, const bf16* __restrict__ Xlo,
                                            int ld, int C, int Kpad,
                                            const void* __restrict__ W, int O, float* __restrict__ P,
                                            const int* __restrict__ flag) {
    __shared__ alignas(16) bf16 Ah[64 * TW], Al[64 * TW], Bh[64 * TW], Bl[64 * TW];
    int isf = *flag;
    int m0 = blockIdx.y * 64, n0 = blockIdx.x * 64;
    int N2 = 2 * O;
    int w = threadIdx.x >> 6, l = threadIdx.x & 63;
    v4f zero = {0.f, 0.f, 0.f, 0.f};
    v4f acc[4] = {zero, zero, zero, zero};
    for (int k0 = 0; k0 < Kpad; k0 += 32) {
        __syncthreads();
        fillA(Ah, Xhi + (size_t)m0 * ld + k0, ld);
        fillA(Al, Xlo + (size_t)m0 * ld + k0, ld);
        {
            int t = threadIdx.x; int r = t >> 2; int kq = (t & 3) << 3;
            int n = n0 + r;
            size_t rowoff = (n < O) ? (size_t)n * 2 * C : (size_t)(n - O) * 2 * C + C;
            for (int j = 0; j < 8; j++) {
                int c = k0 + kq + j;
                float wv = (c < C) ? ldw(W, rowoff + c, isf) : 0.f;
                bf16 h = f2b(wv);
                Bh[r * TW + kq + j] = h;
                Bl[r * TW + kq + j] = f2b(wv - b2f(h));
            }
        }
        __syncthreads();
        v8bf ah = ldfrag(Ah, w, l);
        v8bf al = ldfrag(Al, w, l);
#pragma unroll
        for (int nt = 0; nt < 4; nt++) {
            v8bf bh = ldfrag(Bh, nt, l);
            v8bf bl = ldfrag(Bl, nt, l);
            acc[nt] = __builtin_amdgcn_mfma_f32_16x16x32_bf16(ah, bh, acc[nt], 0, 0, 0);
            acc[nt] = __builtin_amdgcn_mfma_f32_16x16x32_bf16(ah, bl, acc[nt], 0, 0, 0);
            acc[nt] = __builtin_amdgcn_mfma_f32_16x16x32_bf16(al, bh, acc[nt], 0, 0, 0);
        }
    }
    int quad = l >> 4, col = l & 15;
    int rb = m0 + 16 * w + quad * 4;
#pragma unroll
    for (int r = 0; r < 4; r++)
#pragma unroll
        for (int nt = 0; nt < 4; nt++)
            P[(size_t)(rb + r) * N2 + n0 + nt * 16 + col] = acc[nt][r];
}

// ---------------- conv5 via MFMA: Y[m][o] = xc[m][:] . W5[o][:] ----------------
__global__ __launch_bounds__(256) void k_conv5(const bf16* __restrict__ Xhi, const bf16* __restrict__ Xlo,
                                               const void* __restrict__ W, float* __restrict__ Y,
                                               const int* __restrict__ flag) {
    __shared__ alignas(16) bf16 Ah[64 * TW], Al[64 * TW], Bh[64 * TW], Bl[64 * TW];
    int isf = *flag;
    int m0 = blockIdx.y * 64, n0 = blockIdx.x * 64;
    int w = threadIdx.x >> 6, l = threadIdx.x & 63;
    v4f zero = {0.f, 0.f, 0.f, 0.f};
    v4f acc[4] = {zero, zero, zero, zero};
    for (int k0 = 0; k0 < 960; k0 += 32) {
        __syncthreads();
        fillA(Ah, Xhi + (size_t)m0 * 960 + k0, 960);
        fillA(Al, Xlo + (size_t)m0 * 960 + k0, 960);
        {
            int t = threadIdx.x; int r = t >> 2; int kq = (t & 3) << 3;
            size_t rowoff = (size_t)(n0 + r) * 960;
            for (int j = 0; j < 8; j++) {
                float wv = ldw(W, rowoff + k0 + kq + j, isf);
                bf16 h = f2b(wv);
                Bh[r * TW + kq + j] = h;
                Bl[r * TW + kq + j] = f2b(wv - b2f(h));
            }
        }
        __syncthreads();
        v8bf ah = ldfrag(Ah, w, l);
        v8bf al = ldfrag(Al, w, l);
#pragma unroll
        for (int nt = 0; nt < 4; nt++) {
            v8bf bh = ldfrag(Bh, nt, l);
            v8bf bl = ldfrag(Bl, nt, l);
            acc[nt] = __builtin_amdgcn_mfma_f32_16x16x32_bf16(ah, bh, acc[nt], 0, 0, 0);
            acc[nt] = __builtin_amdgcn_mfma_f32_16x16x32_bf16(ah, bl, acc[nt], 0, 0, 0);
            acc[nt] = __builtin_amdgcn_mfma_f32_16x16x32_bf16(al, bh, acc[nt], 0, 0, 0);
        }
    }
    int quad = l >> 4, col = l & 15;
    int rb = m0 + 16 * w + quad * 4;
#pragma unroll
    for (int r = 0; r < 4; r++)
#pragma unroll
        for (int nt = 0; nt < 4; nt++)
            Y[(size_t)(rb + r) * 512 + n0 + nt * 16 + col] = acc[nt][r];
}

// ---------------- gather + affine + lrelu + max over k -> xc hi/lo; fused sq ----------------
__global__ void k_gmax(const float* __restrict__ P, const int* __restrict__ idx,
                       const void* __restrict__ g, const void* __restrict__ bias, int O,
                       bf16* __restrict__ xhOut, bf16* __restrict__ xlOut,
                       float* __restrict__ sqOut, int writeSq, const int* __restrict__ flag) {
    __shared__ int id[20];
    __shared__ float red[512];
    int isf = *flag;
    int n = blockIdx.x;
    int o = threadIdx.x;  // blockDim.x == O
    if (o < 20) id[o] = idx[n * 20 + o];
    __syncthreads();
    int N2 = 2 * O;
    float tv = P[(size_t)n * N2 + O + o] - P[(size_t)n * N2 + o];
    float scl = ldw(g, o, isf) * BN_SCALE;
    float bi = ldw(bias, o, isf);
    float acc = -__builtin_inff();
    for (int j = 0; j < 20; j++) {
        int m = id[j];
        float v = P[(size_t)m * N2 + o] + tv;
        float z = v * scl + bi;
        z = z > 0.f ? z : 0.2f * z;
        acc = fmaxf(acc, z);
    }
    bf16 hi = f2b(acc);
    bf16 lo = f2b(acc - b2f(hi));
    xhOut[(size_t)n * 960 + o] = hi;
    xlOut[(size_t)n * 960 + o] = lo;
    if (writeSq) {
        float xv = b2f(hi) + b2f(lo);
        red[o] = xv * xv;
        __syncthreads();
        for (int s = O >> 1; s > 0; s >>= 1) {
            if (o < s) red[o] += red[o + s];
            __syncthreads();
        }
        if (o == 0) sqOut[n] = red[0];
    }
}

// ---------------- conv5 epilogue: affine + lrelu + max over n ----------------
__global__ void k_pool(const float* __restrict__ Yb, const void* __restrict__ g,
                       const void* __restrict__ bias, float* __restrict__ pooledb,
                       const int* __restrict__ flag) {
    __shared__ float red[4][64];
    int isf = *flag;
    int tx = threadIdx.x & 63, ty = threadIdx.x >> 6;
    int o = blockIdx.x * 64 + tx;
    float scl = ldw(g, o, isf) * BN_SCALE, bi = ldw(bias, o, isf);
    float acc = -__builtin_inff();
    for (int n = ty; n < NPTS; n += 4) {
        float v = Yb[(size_t)n * 512 + o] * scl + bi;
        v = v > 0.f ? v : 0.2f * v;
        acc = fmaxf(acc, v);
    }
    red[ty][tx] = acc;
    __syncthreads();
    if (ty == 0) {
#pragma unroll
        for (int q = 1; q < 4; q++) acc = fmaxf(acc, red[q][tx]);
        pooledb[o] = acc;
    }
}

// ---------------- final linear ----------------
__global__ void k_final(const float* __restrict__ pooled, const void* __restrict__ We,
                        void* __restrict__ out, const int* __restrict__ flag) {
    __shared__ float p[512];
    int isf = *flag;
    int b = blockIdx.x;
    int f = threadIdx.x;
    for (int i = threadIdx.x; i < 512; i += 256) p[i] = pooled[b * 512 + i];
    __syncthreads();
    float acc = 0.f;
    for (int o = 0; o < 512; o++) acc += p[o] * ldw(We, (size_t)f * 512 + o, isf);
    if (isf) ((float*)out)[b * 256 + f] = acc;
    else     ((bf16*)out)[b * 256 + f] = __float2bfloat16(acc);
}

extern "C" void kernel_launch(void* const* d_in, const int* in_sizes, int n_in,
                              void* d_out, int out_size, void* d_ws, size_t ws_size,
                              hipStream_t stream) {
    const void* x  = d_in[0];
    const void* Wl[4] = { d_in[1], d_in[4], d_in[7], d_in[10] };
    const void* gl[4] = { d_in[2], d_in[5], d_in[8], d_in[11] };
    const void* bl[4] = { d_in[3], d_in[6], d_in[9], d_in[12] };
    const void* W5 = d_in[13];
    const void* g5 = d_in[14];
    const void* b5 = d_in[15];
    const void* We = d_in[16];

    // workspace layout (bytes): total 8,351,748 <= 8 MiB
    char* base = (char*)d_ws;
    bf16*  xc_hi  = (bf16*)(base);                   // 1,966,080
    bf16*  xc_lo  = (bf16*)(base + 1966080);         // 1,966,080
    bf16*  xpadh  = (bf16*)(base + 3932160);         // 65,536
    bf16*  xpadl  = (bf16*)(base + 3997696);         // 65,536
    float* DST    = (float*)(base + 4063232);        // 4,194,304 (D | P | Y)
    int*   idxb   = (int*)(base + 8257536);          // 81,920
    float* pooled = (float*)(base + 8339456);        // 8,192
    float* sq     = (float*)(base + 8347648);        // 4,096
    int*   flag   = (int*)(base + 8351744);          // 4

    k_probe<<<1, 256, 0, stream>>>(x, flag);

    const int Cs[4]     = { 3, 64, 128, 256 };
    const int Kpad[4]   = { 32, 64, 128, 256 };
    const int Os[4]     = { 64, 128, 256, 512 };
    const int colIn[4]  = { 0, 0, 64, 192 };
    const int colOut[4] = { 0, 64, 192, 448 };

    for (int b = 0; b < NB; b++) {
        k_xpad<<<4, 256, 0, stream>>>(x, b * NPTS * 3, flag, xpadh, xpadl, sq);
        for (int l = 0; l < 4; l++) {
            int O = Os[l];
            const bf16* Xh = (l == 0) ? xpadh : (xc_hi + colIn[l]);
            const bf16* Xl = (l == 0) ? xpadl : (xc_lo + colIn[l]);
            int ld = (l == 0) ? 32 : 960;
            k_dist<<<dim3(16, 16), 256, 0, stream>>>(Xh, Xl, ld, Kpad[l], sq, DST);
            k_topk<<<NPTS / 4, 256, 0, stream>>>(DST, idxb);
            k_st<<<dim3(2 * O / 64, 16), 256, 0, stream>>>(Xh, Xl, ld, Cs[l], Kpad[l],
                                                           Wl[l], O, DST, flag);
            k_gmax<<<NPTS, O, 0, stream>>>(DST, idxb, gl[l], bl[l], O,
                                           xc_hi + colOut[l], xc_lo + colOut[l], sq, l < 3, flag);
        }
        k_conv5<<<dim3(8, 16), 256, 0, stream>>>(xc_hi, xc_lo, W5, DST, flag);
        k_pool<<<8, 256, 0, stream>>>(DST, g5, b5, pooled + b * 512, flag);
    }
    k_final<<<NB, 256, 0, stream>>>(pooled, We, d_out, flag);
}